// Round 2
// baseline (767.611 us; speedup 1.0000x reference)
//
#include <hip/hip_runtime.h>

typedef unsigned short u16;
typedef short bf16x8 __attribute__((ext_vector_type(8)));
typedef float f32x4 __attribute__((ext_vector_type(4)));
typedef unsigned short us8 __attribute__((ext_vector_type(8)));
typedef unsigned long long u64;

__device__ __forceinline__ u16 f2bf(float f) {
  unsigned u = __float_as_uint(f);
  u += 0x7fffu + ((u >> 16) & 1u);  // RNE (no NaNs in this workload)
  return (u16)(u >> 16);
}
__device__ __forceinline__ float rlf(float v, int l) {
  return __uint_as_float((unsigned)__builtin_amdgcn_readlane(__float_as_int(v), l));
}

// ---------------------------------------------------------------------------
// Workspace layout (bytes)
// ---------------------------------------------------------------------------
#define OFF_L5S 0u            // 64000x384 bf16 = 49,152,000
#define OFF_L6U 49152000u     // 64000x384 bf16
#define OFF_L7S 98304000u     // 65536x384 bf16 = 50,331,648
#define OFF_IDX1 148635648u   // 128x500 int
#define OFF_FPSD 148891648u   // fps dist state (256 KB)
#define OFF_FPSI 149153792u   // fps fidx state
#define OFF_WB   149154304u   // bf16 weight arena (N x Kp)

// ---------------------------------------------------------------------------
// FPS segment: iters [t0,t0+tcnt). Exact fp32, np.argmax first-max tie-break.
// Wave runs at s_setprio(3): it is the serial critical path of the whole net;
// co-resident MLP waves have slack (T5 mechanism).
// ---------------------------------------------------------------------------
template <int CTRL>
__device__ __forceinline__ float dppmaxf(float v) {
  int s = __builtin_amdgcn_update_dpp(0, __float_as_int(v), CTRL, 0xF, 0xF, true);
  return fmaxf(v, __uint_as_float((unsigned)s));
}

__device__ void fps_seg(const float4* cpt, int* out, const int* init1,
                        float* dstate, int* fstate, int b, int t0, int tcnt,
                        int lane) {
  __builtin_amdgcn_s_setprio(3);  // critical serial chain: win issue arbitration
  float px[8], py[8], pz[8], dist[8];
  int base = lane * 8;
#pragma unroll
  for (int j = 0; j < 8; ++j) {
    int p = base + j;
    float4 c = cpt[p < 500 ? p : 0];
    px[j] = c.x; py[j] = c.y; pz[j] = c.z;
  }
  int fidx;
  if (t0 == 0) {
#pragma unroll
    for (int j = 0; j < 8; ++j) dist[j] = 1e10f;
    fidx = init1[b];
  } else {
#pragma unroll
    for (int j = 0; j < 8; ++j) dist[j] = dstate[(b * 64 + lane) * 8 + j];
    fidx = fstate[b];
  }
  float4 c0 = cpt[fidx];
  float cx = c0.x, cy = c0.y, cz = c0.z;

  int tend = t0 + tcnt;
  for (int t = t0; t < tend; ++t) {
    if (lane == 0) out[t] = fidx;
    if (t == 499) return;
#pragma unroll
    for (int j = 0; j < 8; ++j) {
      float dx = __fsub_rn(px[j], cx);
      float dy = __fsub_rn(py[j], cy);
      float dz = __fsub_rn(pz[j], cz);
      float d = __fadd_rn(__fadd_rn(__fmul_rn(dx, dx), __fmul_rn(dy, dy)),
                          __fmul_rn(dz, dz));
      dist[j] = fminf(dist[j], d);
    }
    float m01 = fmaxf(dist[0], dist[1]), m23 = fmaxf(dist[2], dist[3]);
    float m45 = fmaxf(dist[4], dist[5]), m67 = fmaxf(dist[6], dist[7]);
    float lm = fmaxf(fmaxf(m01, m23), fmaxf(m45, m67));
    lm = dppmaxf<0x111>(lm);
    lm = dppmaxf<0x112>(lm);
    lm = dppmaxf<0x114>(lm);
    lm = dppmaxf<0x118>(lm);
    lm = dppmaxf<0x142>(lm);
    lm = dppmaxf<0x143>(lm);
    float mf = rlf(lm, 63);
    int sel = 8;
    float sx = 0.f, sy = 0.f, sz = 0.f;
#pragma unroll
    for (int j = 7; j >= 0; --j) {
      bool hit = (dist[j] == mf);
      sel = hit ? j : sel;
      sx = hit ? px[j] : sx;
      sy = hit ? py[j] : sy;
      sz = hit ? pz[j] : sz;
    }
    u64 mask = __ballot(sel != 8);
    int li = (int)__ffsll(mask) - 1;
    fidx = li * 8 + __builtin_amdgcn_readlane(sel, li);
    cx = rlf(sx, li);
    cy = rlf(sy, li);
    cz = rlf(sz, li);
  }
#pragma unroll
  for (int j = 0; j < 8; ++j) dstate[(b * 64 + lane) * 8 + j] = dist[j];
  if (lane == 0) fstate[b] = fidx;
}

// ---------------------------------------------------------------------------
// Fused-MLP building blocks. 512 threads = 8 waves, grid 2(M) x 4(N).
// A from XOR-swizzled LDS (16B-seg ^ (row&smask)) or per-lane global ptrs
// (nontemporal: stream-once activations must not evict L2-resident weights).
// B (weights, [N][Kp] bf16) streamed from global, L2-resident (normal policy).
// ---------------------------------------------------------------------------
template <int MI, int NI, int NP, int AG, int XC>
__device__ __forceinline__ void gemm_acc(
    f32x4 acc[MI][NI], const u16* __restrict__ aL, int Win, int smask,
    int arow0, const u16* const* aG, const u16* __restrict__ xc,
    const u16* __restrict__ bb, int Kp, int mrow, int quad) {
#pragma unroll
  for (int mi = 0; mi < MI; ++mi)
#pragma unroll
    for (int ni = 0; ni < NI; ++ni) acc[mi][ni] = f32x4{0.f, 0.f, 0.f, 0.f};
#pragma unroll
  for (int kp = 0; kp < NP + XC; ++kp) {
    bf16x8 af[MI];
#pragma unroll
    for (int mi = 0; mi < MI; ++mi) {
      int r = arow0 + mi * 16 + mrow;
      if (XC && kp == NP)
        af[mi] = *(const bf16x8*)(xc + r * 32 + ((quad ^ (r & 3)) << 3));
      else if (AG)
        af[mi] = __builtin_nontemporal_load((const bf16x8*)(aG[mi] + kp * 32));
      else
        af[mi] = *(const bf16x8*)(aL + r * Win +
                                  (((kp * 4 + quad) ^ (r & smask)) << 3));
    }
    bf16x8 bf[NI];
#pragma unroll
    for (int ni = 0; ni < NI; ++ni)
      bf[ni] = *(const bf16x8*)(bb + (size_t)ni * 16 * Kp + kp * 32);
#pragma unroll
    for (int mi = 0; mi < MI; ++mi)
#pragma unroll
      for (int ni = 0; ni < NI; ++ni)
        acc[mi][ni] = __builtin_amdgcn_mfma_f32_16x16x32_bf16(
            af[mi], bf[ni], acc[mi][ni], 0, 0, 0);
  }
}

template <int MI, int NI>
__device__ __forceinline__ void ep_lds(const f32x4 acc[MI][NI], u16* out,
                                       int Wout, const float* __restrict__ bias,
                                       int n0, int arow0, int relu, int mrow,
                                       int quad) {
#pragma unroll
  for (int ni = 0; ni < NI; ++ni) {
    int col = n0 + ni * 16 + mrow;
    float bv = bias[col];
    int seg0 = col >> 3, lo = col & 7;
#pragma unroll
    for (int mi = 0; mi < MI; ++mi)
#pragma unroll
      for (int r = 0; r < 4; ++r) {
        int row = arow0 + mi * 16 + quad * 4 + r;
        float v = acc[mi][ni][r] + bv;
        if (relu) v = fmaxf(v, 0.f);
        out[row * Wout + ((seg0 ^ (row & 7)) << 3) + lo] = f2bf(v);
      }
  }
}

template <int MI, int NI>
__device__ __forceinline__ void ep_glb(const f32x4 acc[MI][NI],
                                       u16* __restrict__ out, int ldo,
                                       const float* __restrict__ bias, int n0,
                                       long grow0, long rowlim, int relu,
                                       int mrow, int quad) {
#pragma unroll
  for (int ni = 0; ni < NI; ++ni) {
    int col = n0 + ni * 16 + mrow;
    float bv = bias[col];
#pragma unroll
    for (int mi = 0; mi < MI; ++mi)
#pragma unroll
      for (int r = 0; r < 4; ++r) {
        long grow = grow0 + mi * 16 + quad * 4 + r;
        if (grow < rowlim) {
          float v = acc[mi][ni][r] + bv;
          if (relu) v = fmaxf(v, 0.f);
          __builtin_nontemporal_store(f2bf(v), &out[(size_t)grow * ldo + col]);
        }
      }
  }
}

// ---------------------------------------------------------------------------
// Fused stage A+B: 96 rows/block, full per-point chain feat->l1->l2->l3->
// (cat x)->l4->l5(global scratch)->l6u(global). FPS blocks first (bid<128).
// LDS: act 48 KB + xcat 6 KB -> 2 blocks/CU.
// ---------------------------------------------------------------------------
struct ABArgs {
  const u16 *w1, *w2, *pc1, *w3, *w4, *pc2;
  const float *b1, *b2, *pc1b, *b3, *b4, *pc2b;
};

__global__ __launch_bounds__(512, 4) void fused_ab(
    ABArgs A, const float* __restrict__ x, const float* __restrict__ cW,
    const float* __restrict__ cb, u16* __restrict__ l5s, u16* __restrict__ l6u,
    const int* __restrict__ init1, int* __restrict__ idx1,
    float* __restrict__ dstate, int* __restrict__ fstate, int t0, int tcnt) {
  __shared__ __align__(16) u16 act[96 * 256];
  __shared__ __align__(16) u16 xcat[96 * 32];
  int bid = blockIdx.x, t = threadIdx.x;
  if (bid < 128) {  // FPS continuation (serial chain overlaps MLP blocks)
    float4* cpt = (float4*)act;
    const float* xb = x + (size_t)bid * 1500;
    for (int p = t; p < 500; p += 512)
      cpt[p] = make_float4(xb[p * 3], xb[p * 3 + 1], xb[p * 3 + 2], 0.f);
    __syncthreads();
    if (t < 64)
      fps_seg(cpt, idx1 + bid * 500, init1, dstate, fstate, bid, t0, tcnt, t);
    return;
  }
  const int blk = bid - 128;
  const size_t rows0 = (size_t)blk * 96;
  // init: feat (conf,x,y,z) into act[W=32]; x into xcat[W=32]
  if (t < 96) {
    size_t gr = rows0 + t;
    if (gr > 63999) gr = 63999;
    float x0 = x[gr * 3], x1 = x[gr * 3 + 1], x2 = x[gr * 3 + 2];
    float z = x0 * cW[0] + x1 * cW[1] + x2 * cW[2] + cb[0];
    float conf = 1.0f / (1.0f + expf(-z));
    us8 fv;
    fv[0] = f2bf(conf); fv[1] = f2bf(x0); fv[2] = f2bf(x1); fv[3] = f2bf(x2);
    fv[4] = 0; fv[5] = 0; fv[6] = 0; fv[7] = 0;
    *(us8*)(act + t * 32 + ((t & 3) << 3)) = fv;
    us8 xv;
    xv[0] = fv[1]; xv[1] = fv[2]; xv[2] = fv[3];
    xv[3] = 0; xv[4] = 0; xv[5] = 0; xv[6] = 0; xv[7] = 0;
    *(us8*)(xcat + t * 32 + ((t & 3) << 3)) = xv;
  }
  if (t < 288) {  // zero pad segs 1..3 of both 32-wide buffers
    us8 zz = {0, 0, 0, 0, 0, 0, 0, 0};
    int r = t / 3, s = 1 + t % 3;
    *(us8*)(act + r * 32 + ((s ^ (r & 3)) << 3)) = zz;
    *(us8*)(xcat + r * 32 + ((s ^ (r & 3)) << 3)) = zz;
  }
  __syncthreads();
  const int w = t >> 6, lane = t & 63, mrow = lane & 15, quad = lane >> 4;
  const int wm = w >> 2, wn = w & 3;
  const int arow0 = wm * 48;
  {  // L1: feat(K=32) -> 64, relu
    f32x4 acc[3][1];
    const u16* bb = A.w1 + (size_t)(wn * 16 + mrow) * 32 + quad * 8;
    gemm_acc<3, 1, 1, 0, 0>(acc, act, 32, 3, arow0, nullptr, nullptr, bb, 32,
                            mrow, quad);
    __syncthreads();
    ep_lds<3, 1>(acc, act, 64, A.b1, wn * 16, arow0, 1, mrow, quad);
    __syncthreads();
  }
  {  // L2: 64 -> 256, relu
    f32x4 acc[3][4];
    const u16* bb = A.w2 + (size_t)(wn * 64 + mrow) * 64 + quad * 8;
    gemm_acc<3, 4, 2, 0, 0>(acc, act, 64, 7, arow0, nullptr, nullptr, bb, 64,
                            mrow, quad);
    __syncthreads();
    ep_lds<3, 4>(acc, act, 256, A.b2, wn * 64, arow0, 1, mrow, quad);
    __syncthreads();
  }
  {  // L3: pc1 256 -> 256, no relu
    f32x4 acc[3][4];
    const u16* bb = A.pc1 + (size_t)(wn * 64 + mrow) * 256 + quad * 8;
    gemm_acc<3, 4, 8, 0, 0>(acc, act, 256, 7, arow0, nullptr, nullptr, bb, 256,
                            mrow, quad);
    __syncthreads();
    ep_lds<3, 4>(acc, act, 256, A.pc1b, wn * 64, arow0, 0, mrow, quad);
    __syncthreads();
  }
  {  // L4: w3 [l3|x](K=256+32) -> 256, relu
    f32x4 acc[3][4];
    const u16* bb = A.w3 + (size_t)(wn * 64 + mrow) * 288 + quad * 8;
    gemm_acc<3, 4, 8, 0, 1>(acc, act, 256, 7, arow0, nullptr, xcat, bb, 288,
                            mrow, quad);
    __syncthreads();
    ep_lds<3, 4>(acc, act, 256, A.b3, wn * 64, arow0, 1, mrow, quad);
    __syncthreads();
  }
  // L5: w4 256 -> 384, relu, to global scratch (2 passes, small acc)
#pragma unroll
  for (int ph = 0; ph < 2; ++ph) {
    f32x4 acc[3][3];
    int n0 = ph * 192 + wn * 48;
    const u16* bb = A.w4 + (size_t)(n0 + mrow) * 256 + quad * 8;
    gemm_acc<3, 3, 8, 0, 0>(acc, act, 256, 7, arow0, nullptr, nullptr, bb, 256,
                            mrow, quad);
    ep_glb<3, 3>(acc, l5s, 384, A.b4, n0, (long)(rows0 + arow0), 64000, 1,
                 mrow, quad);
  }
  __threadfence_block();
  __syncthreads();
  {  // L6: pc2 384 -> 384 (A = own rows of l5s), no relu -> l6u
    const u16* aG[3];
#pragma unroll
    for (int mi = 0; mi < 3; ++mi) {
      size_t r = rows0 + arow0 + mi * 16 + mrow;
      if (r > 63999) r = 63999;
      aG[mi] = l5s + r * 384 + quad * 8;
    }
#pragma unroll
    for (int ph = 0; ph < 2; ++ph) {
      f32x4 acc[3][3];
      int n0 = ph * 192 + wn * 48;
      const u16* bb = A.pc2 + (size_t)(n0 + mrow) * 384 + quad * 8;
      gemm_acc<3, 3, 12, 1, 0>(acc, nullptr, 0, 0, arow0, aG, nullptr, bb, 384,
                               mrow, quad);
      ep_glb<3, 3>(acc, l6u, 384, A.pc2b, n0, (long)(rows0 + arow0), 64000, 0,
                   mrow, quad);
    }
  }
}

// ---------------------------------------------------------------------------
// Fused stage C: 4 blocks/batch x 128 rows. Gathered A (l6u[idx1[p]]) read
// directly via per-lane global ptrs (nt: each row read exactly once — idx1 is
// a permutation); l7 via global scratch; l8 -> col-max.
// ---------------------------------------------------------------------------
struct CArgs {
  const u16 *w5, *w6;
  const float *b5, *b6;
};

__global__ __launch_bounds__(512, 4) void fused_c(
    CArgs C, const float* __restrict__ x, const u16* __restrict__ l6u,
    u16* __restrict__ l7s, float* __restrict__ outf,
    const int* __restrict__ idx1) {
  __shared__ __align__(16) u16 xcat[128 * 32];
  __shared__ float red[2][256];
  int bid = blockIdx.x, t = threadIdx.x;
  const int b = bid >> 2, q = bid & 3;
  const int prow0 = q * 128;
  if (t < 128) {
    int p = prow0 + t, pe = p < 500 ? p : 0;
    const float* xp = x + ((size_t)b * 500 + pe) * 3;
    us8 xv;
    xv[0] = f2bf(xp[0]); xv[1] = f2bf(xp[1]); xv[2] = f2bf(xp[2]);
    xv[3] = 0; xv[4] = 0; xv[5] = 0; xv[6] = 0; xv[7] = 0;
    *(us8*)(xcat + t * 32 + ((t & 3) << 3)) = xv;
  }
  if (t < 384) {
    us8 zz = {0, 0, 0, 0, 0, 0, 0, 0};
    int r = t / 3, s = 1 + t % 3;
    *(us8*)(xcat + r * 32 + ((s ^ (r & 3)) << 3)) = zz;
  }
  __syncthreads();
  const int w = t >> 6, lane = t & 63, mrow = lane & 15, quad = lane >> 4;
  const int wm = w >> 2, wn = w & 3;
  const int arow0 = wm * 64;
  const size_t grow0 = (size_t)b * 512 + prow0 + arow0;
  {  // L7: w5 [l6u_gathered|x](K=384+32) -> 384, relu -> l7s
    const u16* aG[4];
#pragma unroll
    for (int mi = 0; mi < 4; ++mi) {
      int p = prow0 + arow0 + mi * 16 + mrow;
      int pe = p < 500 ? p : 0;
      int s = idx1[b * 500 + pe];
      aG[mi] = l6u + ((size_t)b * 500 + s) * 384 + quad * 8;
    }
#pragma unroll
    for (int ph = 0; ph < 2; ++ph) {
      f32x4 acc[4][3];
      int n0 = ph * 192 + wn * 48;
      const u16* bb = C.w5 + (size_t)(n0 + mrow) * 416 + quad * 8;
      gemm_acc<4, 3, 12, 1, 1>(acc, nullptr, 0, 0, arow0, aG, xcat, bb, 416,
                               mrow, quad);
      ep_glb<4, 3>(acc, l7s, 384, C.b5, n0, (long)grow0, 1L << 30, 1, mrow,
                   quad);
    }
  }
  __threadfence_block();
  __syncthreads();
  {  // L8: w6 384 -> 512 (A = own rows of l7s), relu + per-batch col max
    const u16* aG[4];
#pragma unroll
    for (int mi = 0; mi < 4; ++mi) {
      size_t r = grow0 + mi * 16 + mrow;
      aG[mi] = l7s + r * 384 + quad * 8;
    }
#pragma unroll
    for (int ph = 0; ph < 2; ++ph) {
      f32x4 acc[4][4];
      int n0 = ph * 256 + wn * 64;
      const u16* bb = C.w6 + (size_t)(n0 + mrow) * 384 + quad * 8;
      gemm_acc<4, 4, 12, 1, 0>(acc, nullptr, 0, 0, arow0, aG, nullptr, bb, 384,
                               mrow, quad);
#pragma unroll
      for (int ni = 0; ni < 4; ++ni) {
        int cc = n0 + ni * 16 + mrow;
        float bv = C.b6[cc];
        float mx = 0.f;
#pragma unroll
        for (int mi = 0; mi < 4; ++mi)
#pragma unroll
          for (int r = 0; r < 4; ++r) {
            int p = prow0 + arow0 + mi * 16 + quad * 4 + r;
            float v = fmaxf(acc[mi][ni][r] + bv, 0.f);
            if (p < 500) mx = fmaxf(mx, v);
          }
        mx = fmaxf(mx, __shfl_xor(mx, 16, 64));
        mx = fmaxf(mx, __shfl_xor(mx, 32, 64));
        if (quad == 0) red[wm][wn * 64 + ni * 16 + mrow] = mx;
      }
      __syncthreads();
      if (t < 256) {
        float m = fmaxf(red[0][t], red[1][t]);
        atomicMax((unsigned*)&outf[(size_t)b * 512 + ph * 256 + t],
                  __float_as_uint(m));
      }
      __syncthreads();
    }
  }
}

// ---------------------------------------------------------------------------
// prep: weight convert (N x Kp, k-pad zeros) + outf zero + FPS segment 0
// ---------------------------------------------------------------------------
struct PrepArgs {
  const float* wsrc[8];
  u16* wdst[8];
  int wN[8], wK[8], wKp[8];
  int wstart[9];
};

__global__ __launch_bounds__(256) void prep_kernel(
    PrepArgs pa, const float* __restrict__ x, float* __restrict__ outf,
    const int* __restrict__ init1, int* __restrict__ idx1,
    float* __restrict__ dstate, int* __restrict__ fstate, int tcnt) {
  __shared__ float4 cpt[512];
  int bid = blockIdx.x, t = threadIdx.x;
  if (bid < 128) {
    const float* xb = x + (size_t)bid * 1500;
    for (int p = t; p < 500; p += 256)
      cpt[p] = make_float4(xb[p * 3], xb[p * 3 + 1], xb[p * 3 + 2], 0.f);
    __syncthreads();
    if (t < 64)
      fps_seg(cpt, idx1 + bid * 500, init1, dstate, fstate, bid, 0, tcnt, t);
    return;
  }
  int i = (bid - 128) * 256 + t;
  int S = pa.wstart[8];
  if (i < S) {
    int wsel = 0;
#pragma unroll
    for (int j = 1; j < 8; ++j)
      if (i >= pa.wstart[j]) wsel = j;
    int local = i - pa.wstart[wsel];
    int Kp = pa.wKp[wsel];
    int n = local / Kp, k = local - n * Kp;
    pa.wdst[wsel][local] =
        (k < pa.wK[wsel]) ? f2bf(pa.wsrc[wsel][n * pa.wK[wsel] + k]) : (u16)0;
  } else if (i < S + 65536) {
    outf[i - S] = 0.f;
  }
}

// ---------------------------------------------------------------------------
extern "C" void kernel_launch(void* const* d_in, const int* in_sizes, int n_in,
                              void* d_out, int out_size, void* d_ws,
                              size_t ws_size, hipStream_t stream) {
  const float* x      = (const float*)d_in[0];
  const float* conf_W = (const float*)d_in[1];
  const float* conf_b = (const float*)d_in[2];
  const float* w1     = (const float*)d_in[3];
  const float* b1     = (const float*)d_in[4];
  const float* w2     = (const float*)d_in[5];
  const float* b2     = (const float*)d_in[6];
  const float* pc1_W  = (const float*)d_in[7];
  const float* pc1_b  = (const float*)d_in[8];
  const float* w3     = (const float*)d_in[9];
  const float* b3     = (const float*)d_in[10];
  const float* w4     = (const float*)d_in[11];
  const float* b4     = (const float*)d_in[12];
  const float* pc2_W  = (const float*)d_in[13];
  const float* pc2_b  = (const float*)d_in[14];
  const float* w5     = (const float*)d_in[15];
  const float* b5     = (const float*)d_in[16];
  const float* w6     = (const float*)d_in[17];
  const float* b6     = (const float*)d_in[18];
  const int* init1    = (const int*)d_in[20];

  char* ws = (char*)d_ws;
  u16* l5s = (u16*)(ws + OFF_L5S);
  u16* l6u = (u16*)(ws + OFF_L6U);
  u16* l7s = (u16*)(ws + OFF_L7S);
  int* idx1 = (int*)(ws + OFF_IDX1);
  float* dstate = (float*)(ws + OFF_FPSD);
  int* fstate = (int*)(ws + OFF_FPSI);
  u16* wb = (u16*)(ws + OFF_WB);
  float* outf = (float*)d_out;

  PrepArgs pa;
  const float* srcs[8] = {w1, w2, pc1_W, w3, w4, pc2_W, w5, w6};
  int Ns[8]  = {64, 256, 256, 256, 384, 384, 384, 512};
  int Ks[8]  = {4, 64, 256, 259, 256, 384, 387, 384};
  int Kps[8] = {32, 64, 256, 288, 256, 384, 416, 384};
  u16* WBp[8];
  int cum = 0;
  for (int i = 0; i < 8; ++i) {
    pa.wsrc[i] = srcs[i];
    pa.wdst[i] = WBp[i] = wb + cum;
    pa.wN[i] = Ns[i];
    pa.wK[i] = Ks[i];
    pa.wKp[i] = Kps[i];
    pa.wstart[i] = cum;
    cum += Ns[i] * Kps[i];
  }
  pa.wstart[8] = cum;
  int total = cum + 65536;

  // D1: weights + outf zero + FPS iters [0,64)
  prep_kernel<<<128 + (total + 255) / 256, 256, 0, stream>>>(
      pa, x, outf, init1, idx1, dstate, fstate, 64);

  // D2: fused A+B (667 MLP blocks) + FPS iters [64,500) in first 128 blocks
  ABArgs A;
  A.w1 = WBp[0]; A.w2 = WBp[1]; A.pc1 = WBp[2];
  A.w3 = WBp[3]; A.w4 = WBp[4]; A.pc2 = WBp[5];
  A.b1 = b1; A.b2 = b2; A.pc1b = pc1_b; A.b3 = b3; A.b4 = b4; A.pc2b = pc2_b;
  fused_ab<<<128 + 667, 512, 0, stream>>>(A, x, conf_W, conf_b, l5s, l6u,
                                          init1, idx1, dstate, fstate, 64, 436);

  // D3: fused C (gather + l7 + l8 + max)
  CArgs Cg;
  Cg.w5 = WBp[6]; Cg.w6 = WBp[7]; Cg.b5 = b5; Cg.b6 = b6;
  fused_c<<<512, 512, 0, stream>>>(Cg, x, l6u, l7s, outf, idx1);
}

// Round 3
// 555.434 us; speedup vs baseline: 1.3820x; 1.3820x over previous
//
#include <hip/hip_runtime.h>

typedef unsigned short u16;
typedef short bf16x8 __attribute__((ext_vector_type(8)));
typedef float f32x4 __attribute__((ext_vector_type(4)));
typedef unsigned short us8 __attribute__((ext_vector_type(8)));
typedef unsigned long long u64;

__device__ __forceinline__ u16 f2bf(float f) {
  unsigned u = __float_as_uint(f);
  u += 0x7fffu + ((u >> 16) & 1u);  // RNE (no NaNs in this workload)
  return (u16)(u >> 16);
}
__device__ __forceinline__ float rlf(float v, int l) {
  return __uint_as_float((unsigned)__builtin_amdgcn_readlane(__float_as_int(v), l));
}

// ---------------------------------------------------------------------------
// Workspace layout (bytes). l5/l7 scratch eliminated (LDS-resident now).
// ---------------------------------------------------------------------------
#define OFF_L6U 0u            // 64000x384 bf16 = 49,152,000
#define OFF_IDX1 49152000u    // 128x500 int
#define OFF_FPSD 49408000u    // fps dist state 128*64*8*4 = 262,144
#define OFF_FPSI 49670144u    // fps fidx state 512 B
#define OFF_WB   49671168u    // bf16 weight arena (N x Kp)

// ---------------------------------------------------------------------------
// FPS segment: iters [t0,t0+tcnt). Exact fp32, np.argmax first-max tie-break.
// In fused_ab this wave owns its CU (1 block/CU via 84KB LDS) -> runs at the
// serial-chain arithmetic rate, uncontended.
// ---------------------------------------------------------------------------
template <int CTRL>
__device__ __forceinline__ float dppmaxf(float v) {
  int s = __builtin_amdgcn_update_dpp(0, __float_as_int(v), CTRL, 0xF, 0xF, true);
  return fmaxf(v, __uint_as_float((unsigned)s));
}

__device__ void fps_seg(const float4* cpt, int* out, const int* init1,
                        float* dstate, int* fstate, int b, int t0, int tcnt,
                        int lane) {
  __builtin_amdgcn_s_setprio(3);  // helps in prep where convert blocks co-run
  float px[8], py[8], pz[8], dist[8];
  int base = lane * 8;
#pragma unroll
  for (int j = 0; j < 8; ++j) {
    int p = base + j;
    float4 c = cpt[p < 500 ? p : 0];
    px[j] = c.x; py[j] = c.y; pz[j] = c.z;
  }
  int fidx;
  if (t0 == 0) {
#pragma unroll
    for (int j = 0; j < 8; ++j) dist[j] = 1e10f;
    fidx = init1[b];
  } else {
#pragma unroll
    for (int j = 0; j < 8; ++j) dist[j] = dstate[(b * 64 + lane) * 8 + j];
    fidx = fstate[b];
  }
  float4 c0 = cpt[fidx];
  float cx = c0.x, cy = c0.y, cz = c0.z;

  int tend = t0 + tcnt;
  for (int t = t0; t < tend; ++t) {
    if (lane == 0) out[t] = fidx;
    if (t == 499) return;
#pragma unroll
    for (int j = 0; j < 8; ++j) {
      float dx = __fsub_rn(px[j], cx);
      float dy = __fsub_rn(py[j], cy);
      float dz = __fsub_rn(pz[j], cz);
      float d = __fadd_rn(__fadd_rn(__fmul_rn(dx, dx), __fmul_rn(dy, dy)),
                          __fmul_rn(dz, dz));
      dist[j] = fminf(dist[j], d);
    }
    float m01 = fmaxf(dist[0], dist[1]), m23 = fmaxf(dist[2], dist[3]);
    float m45 = fmaxf(dist[4], dist[5]), m67 = fmaxf(dist[6], dist[7]);
    float lm = fmaxf(fmaxf(m01, m23), fmaxf(m45, m67));
    lm = dppmaxf<0x111>(lm);
    lm = dppmaxf<0x112>(lm);
    lm = dppmaxf<0x114>(lm);
    lm = dppmaxf<0x118>(lm);
    lm = dppmaxf<0x142>(lm);
    lm = dppmaxf<0x143>(lm);
    float mf = rlf(lm, 63);
    int sel = 8;
    float sx = 0.f, sy = 0.f, sz = 0.f;
#pragma unroll
    for (int j = 7; j >= 0; --j) {
      bool hit = (dist[j] == mf);
      sel = hit ? j : sel;
      sx = hit ? px[j] : sx;
      sy = hit ? py[j] : sy;
      sz = hit ? pz[j] : sz;
    }
    u64 mask = __ballot(sel != 8);
    int li = (int)__ffsll(mask) - 1;
    fidx = li * 8 + __builtin_amdgcn_readlane(sel, li);
    cx = rlf(sx, li);
    cy = rlf(sy, li);
    cz = rlf(sz, li);
  }
#pragma unroll
  for (int j = 0; j < 8; ++j) dstate[(b * 64 + lane) * 8 + j] = dist[j];
  if (lane == 0) fstate[b] = fidx;
}

// ---------------------------------------------------------------------------
// Fused-MLP building blocks. 512 threads = 8 waves, grid 2(M) x 4(N).
// A from XOR-swizzled LDS (16B-seg ^ (row&smask)) or per-lane global ptrs.
// B (weights, [N][Kp] bf16) streamed from global (L2-resident).
// ---------------------------------------------------------------------------
template <int MI, int NI, int NP, int AG, int XC>
__device__ __forceinline__ void gemm_acc(
    f32x4 acc[MI][NI], const u16* __restrict__ aL, int Win, int smask,
    int arow0, const u16* const* aG, const u16* __restrict__ xc,
    const u16* __restrict__ bb, int Kp, int mrow, int quad) {
#pragma unroll
  for (int mi = 0; mi < MI; ++mi)
#pragma unroll
    for (int ni = 0; ni < NI; ++ni) acc[mi][ni] = f32x4{0.f, 0.f, 0.f, 0.f};
#pragma unroll
  for (int kp = 0; kp < NP + XC; ++kp) {
    bf16x8 af[MI];
#pragma unroll
    for (int mi = 0; mi < MI; ++mi) {
      int r = arow0 + mi * 16 + mrow;
      if (XC && kp == NP)
        af[mi] = *(const bf16x8*)(xc + r * 32 + ((quad ^ (r & 3)) << 3));
      else if (AG)
        af[mi] = *(const bf16x8*)(aG[mi] + kp * 32);
      else
        af[mi] = *(const bf16x8*)(aL + r * Win +
                                  (((kp * 4 + quad) ^ (r & smask)) << 3));
    }
    bf16x8 bf[NI];
#pragma unroll
    for (int ni = 0; ni < NI; ++ni)
      bf[ni] = *(const bf16x8*)(bb + (size_t)ni * 16 * Kp + kp * 32);
#pragma unroll
    for (int mi = 0; mi < MI; ++mi)
#pragma unroll
      for (int ni = 0; ni < NI; ++ni)
        acc[mi][ni] = __builtin_amdgcn_mfma_f32_16x16x32_bf16(
            af[mi], bf[ni], acc[mi][ni], 0, 0, 0);
  }
}

template <int MI, int NI>
__device__ __forceinline__ void ep_lds(const f32x4 acc[MI][NI], u16* out,
                                       int Wout, const float* __restrict__ bias,
                                       int n0, int arow0, int relu, int mrow,
                                       int quad) {
#pragma unroll
  for (int ni = 0; ni < NI; ++ni) {
    int col = n0 + ni * 16 + mrow;
    float bv = bias[col];
    int seg0 = col >> 3, lo = col & 7;
#pragma unroll
    for (int mi = 0; mi < MI; ++mi)
#pragma unroll
      for (int r = 0; r < 4; ++r) {
        int row = arow0 + mi * 16 + quad * 4 + r;
        float v = acc[mi][ni][r] + bv;
        if (relu) v = fmaxf(v, 0.f);
        out[row * Wout + ((seg0 ^ (row & 7)) << 3) + lo] = f2bf(v);
      }
  }
}

template <int MI, int NI>
__device__ __forceinline__ void ep_glb(const f32x4 acc[MI][NI],
                                       u16* __restrict__ out, int ldo,
                                       const float* __restrict__ bias, int n0,
                                       long grow0, long rowlim, int relu,
                                       int mrow, int quad) {
#pragma unroll
  for (int ni = 0; ni < NI; ++ni) {
    int col = n0 + ni * 16 + mrow;
    float bv = bias[col];
#pragma unroll
    for (int mi = 0; mi < MI; ++mi)
#pragma unroll
      for (int r = 0; r < 4; ++r) {
        long grow = grow0 + mi * 16 + quad * 4 + r;
        if (grow < rowlim) {
          float v = acc[mi][ni][r] + bv;
          if (relu) v = fmaxf(v, 0.f);
          out[(size_t)grow * ldo + col] = f2bf(v);
        }
      }
  }
}

// ---------------------------------------------------------------------------
// Fused stage A+B: 96 rows/block, full chain feat->l1->l2->l3->(cat x)->l4->
// l5(LDS)->l6u(global). Dynamic LDS 84KB -> 1 block/CU: the 128 FPS blocks
// (bid<128) each own a CU; MLP blocks cycle on the remaining 128 CUs.
// LDS map: act 96x384 bf16 (73728 B) + xcat 96x32 (6144 B) + pad.
// ---------------------------------------------------------------------------
struct ABArgs {
  const u16 *w1, *w2, *pc1, *w3, *w4, *pc2;
  const float *b1, *b2, *pc1b, *b3, *b4, *pc2b;
};

#define AB_LDS_BYTES 86016

__global__ __launch_bounds__(512, 2) void fused_ab(
    ABArgs A, const float* __restrict__ x, const float* __restrict__ cW,
    const float* __restrict__ cb, u16* __restrict__ l6u,
    const int* __restrict__ init1, int* __restrict__ idx1,
    float* __restrict__ dstate, int* __restrict__ fstate, int t0, int tcnt) {
  extern __shared__ __align__(16) char smem[];
  u16* act = (u16*)smem;                 // 96 x 384
  u16* xcat = (u16*)(smem + 73728);      // 96 x 32
  int bid = blockIdx.x, t = threadIdx.x;
  if (bid < 128) {  // FPS continuation — dedicated CU
    float4* cpt = (float4*)smem;
    const float* xb = x + (size_t)bid * 1500;
    for (int p = t; p < 500; p += 512)
      cpt[p] = make_float4(xb[p * 3], xb[p * 3 + 1], xb[p * 3 + 2], 0.f);
    __syncthreads();
    if (t < 64)
      fps_seg(cpt, idx1 + bid * 500, init1, dstate, fstate, bid, t0, tcnt, t);
    return;
  }
  const int blk = bid - 128;
  const size_t rows0 = (size_t)blk * 96;
  // init: feat (conf,x,y,z) into act[W=32]; x into xcat[W=32]
  if (t < 96) {
    size_t gr = rows0 + t;
    if (gr > 63999) gr = 63999;
    float x0 = x[gr * 3], x1 = x[gr * 3 + 1], x2 = x[gr * 3 + 2];
    float z = x0 * cW[0] + x1 * cW[1] + x2 * cW[2] + cb[0];
    float conf = 1.0f / (1.0f + expf(-z));
    us8 fv;
    fv[0] = f2bf(conf); fv[1] = f2bf(x0); fv[2] = f2bf(x1); fv[3] = f2bf(x2);
    fv[4] = 0; fv[5] = 0; fv[6] = 0; fv[7] = 0;
    *(us8*)(act + t * 32 + ((t & 3) << 3)) = fv;
    us8 xv;
    xv[0] = fv[1]; xv[1] = fv[2]; xv[2] = fv[3];
    xv[3] = 0; xv[4] = 0; xv[5] = 0; xv[6] = 0; xv[7] = 0;
    *(us8*)(xcat + t * 32 + ((t & 3) << 3)) = xv;
  }
  if (t < 288) {  // zero pad segs 1..3 of both 32-wide buffers
    us8 zz = {0, 0, 0, 0, 0, 0, 0, 0};
    int r = t / 3, s = 1 + t % 3;
    *(us8*)(act + r * 32 + ((s ^ (r & 3)) << 3)) = zz;
    *(us8*)(xcat + r * 32 + ((s ^ (r & 3)) << 3)) = zz;
  }
  __syncthreads();
  const int w = t >> 6, lane = t & 63, mrow = lane & 15, quad = lane >> 4;
  const int wm = w >> 2, wn = w & 3;
  const int arow0 = wm * 48;
  {  // L1: feat(K=32) -> 64, relu
    f32x4 acc[3][1];
    const u16* bb = A.w1 + (size_t)(wn * 16 + mrow) * 32 + quad * 8;
    gemm_acc<3, 1, 1, 0, 0>(acc, act, 32, 3, arow0, nullptr, nullptr, bb, 32,
                            mrow, quad);
    __syncthreads();
    ep_lds<3, 1>(acc, act, 64, A.b1, wn * 16, arow0, 1, mrow, quad);
    __syncthreads();
  }
  {  // L2: 64 -> 256, relu
    f32x4 acc[3][4];
    const u16* bb = A.w2 + (size_t)(wn * 64 + mrow) * 64 + quad * 8;
    gemm_acc<3, 4, 2, 0, 0>(acc, act, 64, 7, arow0, nullptr, nullptr, bb, 64,
                            mrow, quad);
    __syncthreads();
    ep_lds<3, 4>(acc, act, 256, A.b2, wn * 64, arow0, 1, mrow, quad);
    __syncthreads();
  }
  {  // L3: pc1 256 -> 256, no relu
    f32x4 acc[3][4];
    const u16* bb = A.pc1 + (size_t)(wn * 64 + mrow) * 256 + quad * 8;
    gemm_acc<3, 4, 8, 0, 0>(acc, act, 256, 7, arow0, nullptr, nullptr, bb, 256,
                            mrow, quad);
    __syncthreads();
    ep_lds<3, 4>(acc, act, 256, A.pc1b, wn * 64, arow0, 0, mrow, quad);
    __syncthreads();
  }
  {  // L4: w3 [l3|x](K=256+32) -> 256, relu
    f32x4 acc[3][4];
    const u16* bb = A.w3 + (size_t)(wn * 64 + mrow) * 288 + quad * 8;
    gemm_acc<3, 4, 8, 0, 1>(acc, act, 256, 7, arow0, nullptr, xcat, bb, 288,
                            mrow, quad);
    __syncthreads();
    ep_lds<3, 4>(acc, act, 256, A.b3, wn * 64, arow0, 1, mrow, quad);
    __syncthreads();
  }
  {  // L5: w4 256 -> 384, relu, stays in LDS (single pass, acc[3][6])
    f32x4 acc[3][6];
    const u16* bb = A.w4 + (size_t)(wn * 96 + mrow) * 256 + quad * 8;
    gemm_acc<3, 6, 8, 0, 0>(acc, act, 256, 7, arow0, nullptr, nullptr, bb, 256,
                            mrow, quad);
    __syncthreads();
    ep_lds<3, 6>(acc, act, 384, A.b4, wn * 96, arow0, 1, mrow, quad);
    __syncthreads();
  }
  {  // L6: pc2 384 -> 384 (A from LDS), no relu -> l6u global
    f32x4 acc[3][6];
    const u16* bb = A.pc2 + (size_t)(wn * 96 + mrow) * 384 + quad * 8;
    gemm_acc<3, 6, 12, 0, 0>(acc, act, 384, 7, arow0, nullptr, nullptr, bb,
                             384, mrow, quad);
    ep_glb<3, 6>(acc, l6u, 384, A.pc2b, wn * 96, (long)(rows0 + arow0), 64000,
                 0, mrow, quad);
  }
}

// ---------------------------------------------------------------------------
// Fused stage C: 8 blocks/batch x 64 rows. Gathered A (l6u[idx1[p]]) via
// per-lane global ptrs; l7 stays in LDS; l8 -> per-batch col max -> atomicMax.
// LDS: l7 64x384 (48KB) + xcat 4KB + red 2KB = ~55KB -> 2 blocks/CU.
// ---------------------------------------------------------------------------
struct CArgs {
  const u16 *w5, *w6;
  const float *b5, *b6;
};

__global__ __launch_bounds__(512, 4) void fused_c(
    CArgs C, const float* __restrict__ x, const u16* __restrict__ l6u,
    float* __restrict__ outf, const int* __restrict__ idx1) {
  __shared__ __align__(16) u16 l7[64 * 384];
  __shared__ __align__(16) u16 xcat[64 * 32];
  __shared__ float red[2][256];
  int bid = blockIdx.x, t = threadIdx.x;
  const int b = bid >> 3, q = bid & 7;
  const int prow0 = q * 64;
  if (t < 64) {
    int p = prow0 + t, pe = p < 500 ? p : 0;
    const float* xp = x + ((size_t)b * 500 + pe) * 3;
    us8 xv;
    xv[0] = f2bf(xp[0]); xv[1] = f2bf(xp[1]); xv[2] = f2bf(xp[2]);
    xv[3] = 0; xv[4] = 0; xv[5] = 0; xv[6] = 0; xv[7] = 0;
    *(us8*)(xcat + t * 32 + ((t & 3) << 3)) = xv;
  }
  if (t < 192) {
    us8 zz = {0, 0, 0, 0, 0, 0, 0, 0};
    int r = t / 3, s = 1 + t % 3;
    *(us8*)(xcat + r * 32 + ((s ^ (r & 3)) << 3)) = zz;
  }
  __syncthreads();
  const int w = t >> 6, lane = t & 63, mrow = lane & 15, quad = lane >> 4;
  const int wm = w >> 2, wn = w & 3;
  const int arow0 = wm * 32;
  {  // L7: w5 [l6u_gathered|x](K=384+32) -> 384, relu -> l7 LDS
    const u16* aG[2];
#pragma unroll
    for (int mi = 0; mi < 2; ++mi) {
      int p = prow0 + arow0 + mi * 16 + mrow;
      int pe = p < 500 ? p : 0;
      int s = idx1[b * 500 + pe];
      aG[mi] = l6u + ((size_t)b * 500 + s) * 384 + quad * 8;
    }
#pragma unroll
    for (int ph = 0; ph < 2; ++ph) {
      f32x4 acc[2][3];
      int n0 = ph * 192 + wn * 48;
      const u16* bb = C.w5 + (size_t)(n0 + mrow) * 416 + quad * 8;
      gemm_acc<2, 3, 12, 1, 1>(acc, nullptr, 0, 0, arow0, aG, xcat, bb, 416,
                               mrow, quad);
      ep_lds<2, 3>(acc, l7, 384, C.b5, n0, arow0, 1, mrow, quad);
    }
  }
  __syncthreads();
  {  // L8: w6 384 -> 512 (A from l7 LDS), relu + per-batch col max
#pragma unroll
    for (int ph = 0; ph < 2; ++ph) {
      f32x4 acc[2][4];
      int n0 = ph * 256 + wn * 64;
      const u16* bb = C.w6 + (size_t)(n0 + mrow) * 384 + quad * 8;
      gemm_acc<2, 4, 12, 0, 0>(acc, l7, 384, 7, arow0, nullptr, nullptr, bb,
                               384, mrow, quad);
#pragma unroll
      for (int ni = 0; ni < 4; ++ni) {
        int cc = n0 + ni * 16 + mrow;
        float bv = C.b6[cc];
        float mx = 0.f;
#pragma unroll
        for (int mi = 0; mi < 2; ++mi)
#pragma unroll
          for (int r = 0; r < 4; ++r) {
            int p = prow0 + arow0 + mi * 16 + quad * 4 + r;
            float v = fmaxf(acc[mi][ni][r] + bv, 0.f);
            if (p < 500) mx = fmaxf(mx, v);
          }
        mx = fmaxf(mx, __shfl_xor(mx, 16, 64));
        mx = fmaxf(mx, __shfl_xor(mx, 32, 64));
        if (quad == 0) red[wm][wn * 64 + ni * 16 + mrow] = mx;
      }
      __syncthreads();
      if (t < 256) {
        float m = fmaxf(red[0][t], red[1][t]);
        atomicMax((unsigned*)&outf[(size_t)b * 512 + ph * 256 + t],
                  __float_as_uint(m));
      }
      __syncthreads();
    }
  }
}

// ---------------------------------------------------------------------------
// prep: weight convert (N x Kp, k-pad zeros) + outf zero + FPS segment 0
// ---------------------------------------------------------------------------
struct PrepArgs {
  const float* wsrc[8];
  u16* wdst[8];
  int wN[8], wK[8], wKp[8];
  int wstart[9];
};

__global__ __launch_bounds__(256) void prep_kernel(
    PrepArgs pa, const float* __restrict__ x, float* __restrict__ outf,
    const int* __restrict__ init1, int* __restrict__ idx1,
    float* __restrict__ dstate, int* __restrict__ fstate, int tcnt) {
  __shared__ float4 cpt[512];
  int bid = blockIdx.x, t = threadIdx.x;
  if (bid < 128) {
    const float* xb = x + (size_t)bid * 1500;
    for (int p = t; p < 500; p += 256)
      cpt[p] = make_float4(xb[p * 3], xb[p * 3 + 1], xb[p * 3 + 2], 0.f);
    __syncthreads();
    if (t < 64)
      fps_seg(cpt, idx1 + bid * 500, init1, dstate, fstate, bid, 0, tcnt, t);
    return;
  }
  int i = (bid - 128) * 256 + t;
  int S = pa.wstart[8];
  if (i < S) {
    int wsel = 0;
#pragma unroll
    for (int j = 1; j < 8; ++j)
      if (i >= pa.wstart[j]) wsel = j;
    int local = i - pa.wstart[wsel];
    int Kp = pa.wKp[wsel];
    int n = local / Kp, k = local - n * Kp;
    pa.wdst[wsel][local] =
        (k < pa.wK[wsel]) ? f2bf(pa.wsrc[wsel][n * pa.wK[wsel] + k]) : (u16)0;
  } else if (i < S + 65536) {
    outf[i - S] = 0.f;
  }
}

// ---------------------------------------------------------------------------
extern "C" void kernel_launch(void* const* d_in, const int* in_sizes, int n_in,
                              void* d_out, int out_size, void* d_ws,
                              size_t ws_size, hipStream_t stream) {
  const float* x      = (const float*)d_in[0];
  const float* conf_W = (const float*)d_in[1];
  const float* conf_b = (const float*)d_in[2];
  const float* w1     = (const float*)d_in[3];
  const float* b1     = (const float*)d_in[4];
  const float* w2     = (const float*)d_in[5];
  const float* b2     = (const float*)d_in[6];
  const float* pc1_W  = (const float*)d_in[7];
  const float* pc1_b  = (const float*)d_in[8];
  const float* w3     = (const float*)d_in[9];
  const float* b3     = (const float*)d_in[10];
  const float* w4     = (const float*)d_in[11];
  const float* b4     = (const float*)d_in[12];
  const float* pc2_W  = (const float*)d_in[13];
  const float* pc2_b  = (const float*)d_in[14];
  const float* w5     = (const float*)d_in[15];
  const float* b5     = (const float*)d_in[16];
  const float* w6     = (const float*)d_in[17];
  const float* b6     = (const float*)d_in[18];
  const int* init1    = (const int*)d_in[20];

  char* ws = (char*)d_ws;
  u16* l6u = (u16*)(ws + OFF_L6U);
  int* idx1 = (int*)(ws + OFF_IDX1);
  float* dstate = (float*)(ws + OFF_FPSD);
  int* fstate = (int*)(ws + OFF_FPSI);
  u16* wb = (u16*)(ws + OFF_WB);
  float* outf = (float*)d_out;

  PrepArgs pa;
  const float* srcs[8] = {w1, w2, pc1_W, w3, w4, pc2_W, w5, w6};
  int Ns[8]  = {64, 256, 256, 256, 384, 384, 384, 512};
  int Ks[8]  = {4, 64, 256, 259, 256, 384, 387, 384};
  int Kps[8] = {32, 64, 256, 288, 256, 384, 416, 384};
  u16* WBp[8];
  int cum = 0;
  for (int i = 0; i < 8; ++i) {
    pa.wsrc[i] = srcs[i];
    pa.wdst[i] = WBp[i] = wb + cum;
    pa.wN[i] = Ns[i];
    pa.wK[i] = Ks[i];
    pa.wKp[i] = Kps[i];
    pa.wstart[i] = cum;
    cum += Ns[i] * Kps[i];
  }
  pa.wstart[8] = cum;
  int total = cum + 65536;

  // D1: weights + outf zero + FPS iters [0,64)
  prep_kernel<<<128 + (total + 255) / 256, 256, 0, stream>>>(
      pa, x, outf, init1, idx1, dstate, fstate, 64);

  // D2: fused A+B (667 MLP blocks) + FPS iters [64,500). 84KB dynamic LDS ->
  // 1 block/CU: FPS blocks get dedicated CUs.
  ABArgs A;
  A.w1 = WBp[0]; A.w2 = WBp[1]; A.pc1 = WBp[2];
  A.w3 = WBp[3]; A.w4 = WBp[4]; A.pc2 = WBp[5];
  A.b1 = b1; A.b2 = b2; A.pc1b = pc1_b; A.b3 = b3; A.b4 = b4; A.pc2b = pc2_b;
  fused_ab<<<128 + 667, 512, AB_LDS_BYTES, stream>>>(
      A, x, conf_W, conf_b, l6u, init1, idx1, dstate, fstate, 64, 436);

  // D3: fused C (gather + l7(LDS) + l8 + max)
  CArgs Cg;
  Cg.w5 = WBp[6]; Cg.w6 = WBp[7]; Cg.b5 = b5; Cg.b6 = b6;
  fused_c<<<1024, 512, 0, stream>>>(Cg, x, l6u, outf, idx1);
}

// Round 4
// 440.453 us; speedup vs baseline: 1.7428x; 1.2611x over previous
//
#include <hip/hip_runtime.h>

typedef unsigned short u16;
typedef short bf16x8 __attribute__((ext_vector_type(8)));
typedef float f32x4 __attribute__((ext_vector_type(4)));
typedef unsigned short us8 __attribute__((ext_vector_type(8)));
typedef unsigned long long u64;

__device__ __forceinline__ u16 f2bf(float f) {
  unsigned u = __float_as_uint(f);
  u += 0x7fffu + ((u >> 16) & 1u);  // RNE (no NaNs in this workload)
  return (u16)(u >> 16);
}
__device__ __forceinline__ float rlf(float v, int l) {
  return __uint_as_float((unsigned)__builtin_amdgcn_readlane(__float_as_int(v), l));
}

// ---------------------------------------------------------------------------
// Workspace layout (bytes)
// ---------------------------------------------------------------------------
#define OFF_L6U 0u            // 64000x384 bf16 = 49,152,000
#define OFF_IDX1 49152000u    // 128x500 int
#define OFF_FPSD 49408000u    // fps dist state
#define OFF_FPSI 49670144u    // fps fidx state
#define OFF_WB   49671168u    // bf16 weight arena (N x Kp)

// ---------------------------------------------------------------------------
// FPS: u64-key formulation. key = (dist_bits<<32) | ~idx  (dist>=0 so integer
// order == float order; ties -> smaller idx wins == np.argmax first-max; the
// >=500 duplicate slots have larger idx -> never beat the real point).
// Per-lane 8->1 cndmask tree + 6-step DPP directional reduce, both CARRYING
// the winner's coords. Tail = 4 readlanes from lane 63 (no tie-scan/ballot).
// ---------------------------------------------------------------------------
template <int CTRL>
__device__ __forceinline__ unsigned dppu(unsigned v) {
  return (unsigned)__builtin_amdgcn_update_dpp(0, (int)v, CTRL, 0xF, 0xF, true);
}
template <int CTRL>
__device__ __forceinline__ float dppf(float v) {
  return __uint_as_float(dppu<CTRL>(__float_as_uint(v)));
}
__device__ __forceinline__ void ksel(u64& ak, float& ax, float& ay, float& az,
                                     u64 bk, float bx, float by, float bz) {
  bool g = bk > ak;
  ak = g ? bk : ak;
  ax = g ? bx : ax;
  ay = g ? by : ay;
  az = g ? bz : az;
}
template <int CTRL>
__device__ __forceinline__ void redstep(u64& k, float& x, float& y, float& z) {
  unsigned lo = (unsigned)k, hi = (unsigned)(k >> 32);
  unsigned olo = dppu<CTRL>(lo), ohi = dppu<CTRL>(hi);
  float ox = dppf<CTRL>(x), oy = dppf<CTRL>(y), oz = dppf<CTRL>(z);
  u64 ok = (((u64)ohi) << 32) | olo;
  ksel(k, x, y, z, ok, ox, oy, oz);
}

__device__ void fps_seg(const float4* cpt, int* out, const int* init1,
                        float* dstate, int* fstate, int b, int t0, int tcnt,
                        int lane) {
  __builtin_amdgcn_s_setprio(3);
  float px[8], py[8], pz[8], dist[8];
  unsigned nl[8];
  int base = lane * 8;
#pragma unroll
  for (int j = 0; j < 8; ++j) {
    int p = base + j;
    float4 c = cpt[p < 500 ? p : 0];
    px[j] = c.x; py[j] = c.y; pz[j] = c.z;
    nl[j] = ~(unsigned)p;
  }
  int fidx;
  if (t0 == 0) {
#pragma unroll
    for (int j = 0; j < 8; ++j) dist[j] = 1e10f;
    fidx = init1[b];
  } else {
#pragma unroll
    for (int j = 0; j < 8; ++j) dist[j] = dstate[(b * 64 + lane) * 8 + j];
    fidx = fstate[b];
  }
  float4 c0 = cpt[fidx];
  float cx = c0.x, cy = c0.y, cz = c0.z;

  int tend = t0 + tcnt;
  for (int t = t0; t < tend; ++t) {
    if (lane == 0) out[t] = fidx;
    if (t == 499) return;
#pragma unroll
    for (int j = 0; j < 8; ++j) {
      float dx = __fsub_rn(px[j], cx);
      float dy = __fsub_rn(py[j], cy);
      float dz = __fsub_rn(pz[j], cz);
      float d = __fadd_rn(__fadd_rn(__fmul_rn(dx, dx), __fmul_rn(dy, dy)),
                          __fmul_rn(dz, dz));
      dist[j] = fminf(dist[j], d);
    }
    // per-lane 8 -> 4 (select coords straight from px/py/pz, no copies)
    u64 k[4];
    float X[4], Y[4], Z[4];
#pragma unroll
    for (int j = 0; j < 4; ++j) {
      u64 ka = (((u64)__float_as_uint(dist[2 * j])) << 32) | nl[2 * j];
      u64 kb = (((u64)__float_as_uint(dist[2 * j + 1])) << 32) | nl[2 * j + 1];
      bool g = kb > ka;
      k[j] = g ? kb : ka;
      X[j] = g ? px[2 * j + 1] : px[2 * j];
      Y[j] = g ? py[2 * j + 1] : py[2 * j];
      Z[j] = g ? pz[2 * j + 1] : pz[2 * j];
    }
    ksel(k[0], X[0], Y[0], Z[0], k[1], X[1], Y[1], Z[1]);
    ksel(k[2], X[2], Y[2], Z[2], k[3], X[3], Y[3], Z[3]);
    ksel(k[0], X[0], Y[0], Z[0], k[2], X[2], Y[2], Z[2]);
    // wave reduce (directional; final winner in lane 63)
    redstep<0x111>(k[0], X[0], Y[0], Z[0]);
    redstep<0x112>(k[0], X[0], Y[0], Z[0]);
    redstep<0x114>(k[0], X[0], Y[0], Z[0]);
    redstep<0x118>(k[0], X[0], Y[0], Z[0]);
    redstep<0x142>(k[0], X[0], Y[0], Z[0]);
    redstep<0x143>(k[0], X[0], Y[0], Z[0]);
    unsigned wlo = (unsigned)__builtin_amdgcn_readlane((int)(unsigned)k[0], 63);
    fidx = (int)(~wlo);
    cx = rlf(X[0], 63);
    cy = rlf(Y[0], 63);
    cz = rlf(Z[0], 63);
  }
#pragma unroll
  for (int j = 0; j < 8; ++j) dstate[(b * 64 + lane) * 8 + j] = dist[j];
  if (lane == 0) fstate[b] = fidx;
}

// ---------------------------------------------------------------------------
// Fused-MLP building blocks. 512 threads = 8 waves, grid 2(M) x 4(N).
// ---------------------------------------------------------------------------
template <int MI, int NI, int NP, int AG, int XC>
__device__ __forceinline__ void gemm_acc(
    f32x4 acc[MI][NI], const u16* __restrict__ aL, int Win, int smask,
    int arow0, const u16* const* aG, const u16* __restrict__ xc,
    const u16* __restrict__ bb, int Kp, int mrow, int quad) {
#pragma unroll
  for (int mi = 0; mi < MI; ++mi)
#pragma unroll
    for (int ni = 0; ni < NI; ++ni) acc[mi][ni] = f32x4{0.f, 0.f, 0.f, 0.f};
#pragma unroll
  for (int kp = 0; kp < NP + XC; ++kp) {
    bf16x8 af[MI];
#pragma unroll
    for (int mi = 0; mi < MI; ++mi) {
      int r = arow0 + mi * 16 + mrow;
      if (XC && kp == NP)
        af[mi] = *(const bf16x8*)(xc + r * 32 + ((quad ^ (r & 3)) << 3));
      else if (AG)
        af[mi] = *(const bf16x8*)(aG[mi] + kp * 32);
      else
        af[mi] = *(const bf16x8*)(aL + r * Win +
                                  (((kp * 4 + quad) ^ (r & smask)) << 3));
    }
    bf16x8 bf[NI];
#pragma unroll
    for (int ni = 0; ni < NI; ++ni)
      bf[ni] = *(const bf16x8*)(bb + (size_t)ni * 16 * Kp + kp * 32);
#pragma unroll
    for (int mi = 0; mi < MI; ++mi)
#pragma unroll
      for (int ni = 0; ni < NI; ++ni)
        acc[mi][ni] = __builtin_amdgcn_mfma_f32_16x16x32_bf16(
            af[mi], bf[ni], acc[mi][ni], 0, 0, 0);
  }
}

template <int MI, int NI>
__device__ __forceinline__ void ep_lds(const f32x4 acc[MI][NI], u16* out,
                                       int Wout, const float* __restrict__ bias,
                                       int n0, int arow0, int relu, int mrow,
                                       int quad) {
#pragma unroll
  for (int ni = 0; ni < NI; ++ni) {
    int col = n0 + ni * 16 + mrow;
    float bv = bias[col];
    int seg0 = col >> 3, lo = col & 7;
#pragma unroll
    for (int mi = 0; mi < MI; ++mi)
#pragma unroll
      for (int r = 0; r < 4; ++r) {
        int row = arow0 + mi * 16 + quad * 4 + r;
        float v = acc[mi][ni][r] + bv;
        if (relu) v = fmaxf(v, 0.f);
        out[row * Wout + ((seg0 ^ (row & 7)) << 3) + lo] = f2bf(v);
      }
  }
}

template <int MI, int NI>
__device__ __forceinline__ void ep_glb(const f32x4 acc[MI][NI],
                                       u16* __restrict__ out, int ldo,
                                       const float* __restrict__ bias, int n0,
                                       long grow0, long rowlim, int relu,
                                       int mrow, int quad) {
#pragma unroll
  for (int ni = 0; ni < NI; ++ni) {
    int col = n0 + ni * 16 + mrow;
    float bv = bias[col];
#pragma unroll
    for (int mi = 0; mi < MI; ++mi)
#pragma unroll
      for (int r = 0; r < 4; ++r) {
        long grow = grow0 + mi * 16 + quad * 4 + r;
        if (grow < rowlim) {
          float v = acc[mi][ni][r] + bv;
          if (relu) v = fmaxf(v, 0.f);
          out[(size_t)grow * ldo + col] = f2bf(v);
        }
      }
  }
}

// ---------------------------------------------------------------------------
// Fused stage A+B: 128 rows/block (500 blocks -> 25% less weight traffic than
// 96-row blocks), chain feat->l1->l2->l3->(cat x)->l4->l5(LDS)->l6u(global).
// Dynamic LDS 104 KB -> 1 block/CU; FPS blocks (bid<128) own their CUs.
// ---------------------------------------------------------------------------
struct ABArgs {
  const u16 *w1, *w2, *pc1, *w3, *w4, *pc2;
  const float *b1, *b2, *pc1b, *b3, *b4, *pc2b;
};

#define AB_LDS_BYTES (98304 + 8192)

__global__ __launch_bounds__(512, 2) void fused_ab(
    ABArgs A, const float* __restrict__ x, const float* __restrict__ cW,
    const float* __restrict__ cb, u16* __restrict__ l6u,
    const int* __restrict__ init1, int* __restrict__ idx1,
    float* __restrict__ dstate, int* __restrict__ fstate, int t0, int tcnt) {
  extern __shared__ __align__(16) char smem[];
  u16* act = (u16*)smem;             // 128 x up-to-384
  u16* xcat = (u16*)(smem + 98304);  // 128 x 32
  int bid = blockIdx.x, t = threadIdx.x;
  if (bid < 128) {  // FPS continuation — dedicated CU
    float4* cpt = (float4*)smem;
    const float* xb = x + (size_t)bid * 1500;
    for (int p = t; p < 500; p += 512)
      cpt[p] = make_float4(xb[p * 3], xb[p * 3 + 1], xb[p * 3 + 2], 0.f);
    __syncthreads();
    if (t < 64)
      fps_seg(cpt, idx1 + bid * 500, init1, dstate, fstate, bid, t0, tcnt, t);
    return;
  }
  const int blk = bid - 128;
  const size_t rows0 = (size_t)blk * 128;
  // init: feat (conf,x,y,z) into act[W=32]; x into xcat[W=32]
  if (t < 128) {
    size_t gr = rows0 + t;
    float x0 = x[gr * 3], x1 = x[gr * 3 + 1], x2 = x[gr * 3 + 2];
    float z = x0 * cW[0] + x1 * cW[1] + x2 * cW[2] + cb[0];
    float conf = 1.0f / (1.0f + expf(-z));
    us8 fv;
    fv[0] = f2bf(conf); fv[1] = f2bf(x0); fv[2] = f2bf(x1); fv[3] = f2bf(x2);
    fv[4] = 0; fv[5] = 0; fv[6] = 0; fv[7] = 0;
    *(us8*)(act + t * 32 + ((t & 3) << 3)) = fv;
    us8 xv;
    xv[0] = fv[1]; xv[1] = fv[2]; xv[2] = fv[3];
    xv[3] = 0; xv[4] = 0; xv[5] = 0; xv[6] = 0; xv[7] = 0;
    *(us8*)(xcat + t * 32 + ((t & 3) << 3)) = xv;
  }
  if (t < 384) {  // zero pad segs 1..3 of both 32-wide buffers
    us8 zz = {0, 0, 0, 0, 0, 0, 0, 0};
    int r = t / 3, s = 1 + t % 3;
    *(us8*)(act + r * 32 + ((s ^ (r & 3)) << 3)) = zz;
    *(us8*)(xcat + r * 32 + ((s ^ (r & 3)) << 3)) = zz;
  }
  __syncthreads();
  const int w = t >> 6, lane = t & 63, mrow = lane & 15, quad = lane >> 4;
  const int wm = w >> 2, wn = w & 3;
  const int arow0 = wm * 64;
  {  // L1: feat(K=32) -> 64, relu
    f32x4 acc[4][1];
    const u16* bb = A.w1 + (size_t)(wn * 16 + mrow) * 32 + quad * 8;
    gemm_acc<4, 1, 1, 0, 0>(acc, act, 32, 3, arow0, nullptr, nullptr, bb, 32,
                            mrow, quad);
    __syncthreads();
    ep_lds<4, 1>(acc, act, 64, A.b1, wn * 16, arow0, 1, mrow, quad);
    __syncthreads();
  }
  {  // L2: 64 -> 256, relu
    f32x4 acc[4][4];
    const u16* bb = A.w2 + (size_t)(wn * 64 + mrow) * 64 + quad * 8;
    gemm_acc<4, 4, 2, 0, 0>(acc, act, 64, 7, arow0, nullptr, nullptr, bb, 64,
                            mrow, quad);
    __syncthreads();
    ep_lds<4, 4>(acc, act, 256, A.b2, wn * 64, arow0, 1, mrow, quad);
    __syncthreads();
  }
  {  // L3: pc1 256 -> 256, no relu
    f32x4 acc[4][4];
    const u16* bb = A.pc1 + (size_t)(wn * 64 + mrow) * 256 + quad * 8;
    gemm_acc<4, 4, 8, 0, 0>(acc, act, 256, 7, arow0, nullptr, nullptr, bb, 256,
                            mrow, quad);
    __syncthreads();
    ep_lds<4, 4>(acc, act, 256, A.pc1b, wn * 64, arow0, 0, mrow, quad);
    __syncthreads();
  }
  {  // L4: w3 [l3|x](K=256+32) -> 256, relu
    f32x4 acc[4][4];
    const u16* bb = A.w3 + (size_t)(wn * 64 + mrow) * 288 + quad * 8;
    gemm_acc<4, 4, 8, 0, 1>(acc, act, 256, 7, arow0, nullptr, xcat, bb, 288,
                            mrow, quad);
    __syncthreads();
    ep_lds<4, 4>(acc, act, 256, A.b3, wn * 64, arow0, 1, mrow, quad);
    __syncthreads();
  }
  {  // L5: w4 256 -> 384, relu, stays in LDS
    f32x4 acc[4][6];
    const u16* bb = A.w4 + (size_t)(wn * 96 + mrow) * 256 + quad * 8;
    gemm_acc<4, 6, 8, 0, 0>(acc, act, 256, 7, arow0, nullptr, nullptr, bb, 256,
                            mrow, quad);
    __syncthreads();
    ep_lds<4, 6>(acc, act, 384, A.b4, wn * 96, arow0, 1, mrow, quad);
    __syncthreads();
  }
  {  // L6: pc2 384 -> 384 (A from LDS), no relu -> l6u global
    f32x4 acc[4][6];
    const u16* bb = A.pc2 + (size_t)(wn * 96 + mrow) * 384 + quad * 8;
    gemm_acc<4, 6, 12, 0, 0>(acc, act, 384, 7, arow0, nullptr, nullptr, bb,
                             384, mrow, quad);
    ep_glb<4, 6>(acc, l6u, 384, A.pc2b, wn * 96, (long)(rows0 + arow0), 64000,
                 0, mrow, quad);
  }
}

// ---------------------------------------------------------------------------
// Fused stage C: 4 blocks/batch x 128 rows (512 blocks -> half the weight
// traffic of 64-row blocks). Gathered A (l6u[idx1[p]]) via per-lane global
// ptrs; l7 stays in LDS; l8 -> per-batch col max -> atomicMax.
// Dynamic LDS: l7 96KB + xcat 8KB + red 2KB = 106KB -> 1 block/CU.
// ---------------------------------------------------------------------------
struct CArgs {
  const u16 *w5, *w6;
  const float *b5, *b6;
};

#define C_LDS_BYTES (98304 + 8192 + 2048)

__global__ __launch_bounds__(512, 2) void fused_c(
    CArgs C, const float* __restrict__ x, const u16* __restrict__ l6u,
    float* __restrict__ outf, const int* __restrict__ idx1) {
  extern __shared__ __align__(16) char smem[];
  u16* l7 = (u16*)smem;                       // 128 x 384
  u16* xcat = (u16*)(smem + 98304);           // 128 x 32
  float* red = (float*)(smem + 98304 + 8192); // 2 x 256
  int bid = blockIdx.x, t = threadIdx.x;
  const int b = bid >> 2, q = bid & 3;
  const int prow0 = q * 128;
  if (t < 128) {
    int p = prow0 + t, pe = p < 500 ? p : 0;
    const float* xp = x + ((size_t)b * 500 + pe) * 3;
    us8 xv;
    xv[0] = f2bf(xp[0]); xv[1] = f2bf(xp[1]); xv[2] = f2bf(xp[2]);
    xv[3] = 0; xv[4] = 0; xv[5] = 0; xv[6] = 0; xv[7] = 0;
    *(us8*)(xcat + t * 32 + ((t & 3) << 3)) = xv;
  }
  if (t < 384) {
    us8 zz = {0, 0, 0, 0, 0, 0, 0, 0};
    int r = t / 3, s = 1 + t % 3;
    *(us8*)(xcat + r * 32 + ((s ^ (r & 3)) << 3)) = zz;
  }
  __syncthreads();
  const int w = t >> 6, lane = t & 63, mrow = lane & 15, quad = lane >> 4;
  const int wm = w >> 2, wn = w & 3;
  const int arow0 = wm * 64;
  {  // L7: w5 [l6u_gathered|x](K=384+32) -> 384, relu -> l7 LDS
    const u16* aG[4];
#pragma unroll
    for (int mi = 0; mi < 4; ++mi) {
      int p = prow0 + arow0 + mi * 16 + mrow;
      int pe = p < 500 ? p : 0;
      int s = idx1[b * 500 + pe];
      aG[mi] = l6u + ((size_t)b * 500 + s) * 384 + quad * 8;
    }
    f32x4 acc[4][6];
    const u16* bb = C.w5 + (size_t)(wn * 96 + mrow) * 416 + quad * 8;
    gemm_acc<4, 6, 12, 1, 1>(acc, nullptr, 0, 0, arow0, aG, xcat, bb, 416,
                             mrow, quad);
    ep_lds<4, 6>(acc, l7, 384, C.b5, wn * 96, arow0, 1, mrow, quad);
  }
  __syncthreads();
  {  // L8: w6 384 -> 512 (A from l7 LDS), relu + per-batch col max
#pragma unroll
    for (int ph = 0; ph < 2; ++ph) {
      f32x4 acc[4][4];
      int n0 = ph * 256 + wn * 64;
      const u16* bb = C.w6 + (size_t)(n0 + mrow) * 384 + quad * 8;
      gemm_acc<4, 4, 12, 0, 0>(acc, l7, 384, 7, arow0, nullptr, nullptr, bb,
                               384, mrow, quad);
#pragma unroll
      for (int ni = 0; ni < 4; ++ni) {
        int cc = n0 + ni * 16 + mrow;
        float bv = C.b6[cc];
        float mx = 0.f;
#pragma unroll
        for (int mi = 0; mi < 4; ++mi)
#pragma unroll
          for (int r = 0; r < 4; ++r) {
            int p = prow0 + arow0 + mi * 16 + quad * 4 + r;
            float v = fmaxf(acc[mi][ni][r] + bv, 0.f);
            if (p < 500) mx = fmaxf(mx, v);
          }
        mx = fmaxf(mx, __shfl_xor(mx, 16, 64));
        mx = fmaxf(mx, __shfl_xor(mx, 32, 64));
        if (quad == 0) red[wm * 256 + wn * 64 + ni * 16 + mrow] = mx;
      }
      __syncthreads();
      if (t < 256) {
        float m = fmaxf(red[t], red[256 + t]);
        atomicMax((unsigned*)&outf[(size_t)b * 512 + ph * 256 + t],
                  __float_as_uint(m));
      }
      __syncthreads();
    }
  }
}

// ---------------------------------------------------------------------------
// prep: weight convert (N x Kp, k-pad zeros) + outf zero + FPS segment 0
// ---------------------------------------------------------------------------
struct PrepArgs {
  const float* wsrc[8];
  u16* wdst[8];
  int wN[8], wK[8], wKp[8];
  int wstart[9];
};

__global__ __launch_bounds__(256) void prep_kernel(
    PrepArgs pa, const float* __restrict__ x, float* __restrict__ outf,
    const int* __restrict__ init1, int* __restrict__ idx1,
    float* __restrict__ dstate, int* __restrict__ fstate, int tcnt) {
  __shared__ float4 cpt[512];
  int bid = blockIdx.x, t = threadIdx.x;
  if (bid < 128) {
    const float* xb = x + (size_t)bid * 1500;
    for (int p = t; p < 500; p += 256)
      cpt[p] = make_float4(xb[p * 3], xb[p * 3 + 1], xb[p * 3 + 2], 0.f);
    __syncthreads();
    if (t < 64)
      fps_seg(cpt, idx1 + bid * 500, init1, dstate, fstate, bid, 0, tcnt, t);
    return;
  }
  int i = (bid - 128) * 256 + t;
  int S = pa.wstart[8];
  if (i < S) {
    int wsel = 0;
#pragma unroll
    for (int j = 1; j < 8; ++j)
      if (i >= pa.wstart[j]) wsel = j;
    int local = i - pa.wstart[wsel];
    int Kp = pa.wKp[wsel];
    int n = local / Kp, k = local - n * Kp;
    pa.wdst[wsel][local] =
        (k < pa.wK[wsel]) ? f2bf(pa.wsrc[wsel][n * pa.wK[wsel] + k]) : (u16)0;
  } else if (i < S + 65536) {
    outf[i - S] = 0.f;
  }
}

// ---------------------------------------------------------------------------
extern "C" void kernel_launch(void* const* d_in, const int* in_sizes, int n_in,
                              void* d_out, int out_size, void* d_ws,
                              size_t ws_size, hipStream_t stream) {
  const float* x      = (const float*)d_in[0];
  const float* conf_W = (const float*)d_in[1];
  const float* conf_b = (const float*)d_in[2];
  const float* w1     = (const float*)d_in[3];
  const float* b1     = (const float*)d_in[4];
  const float* w2     = (const float*)d_in[5];
  const float* b2     = (const float*)d_in[6];
  const float* pc1_W  = (const float*)d_in[7];
  const float* pc1_b  = (const float*)d_in[8];
  const float* w3     = (const float*)d_in[9];
  const float* b3     = (const float*)d_in[10];
  const float* w4     = (const float*)d_in[11];
  const float* b4     = (const float*)d_in[12];
  const float* pc2_W  = (const float*)d_in[13];
  const float* pc2_b  = (const float*)d_in[14];
  const float* w5     = (const float*)d_in[15];
  const float* b5     = (const float*)d_in[16];
  const float* w6     = (const float*)d_in[17];
  const float* b6     = (const float*)d_in[18];
  const int* init1    = (const int*)d_in[20];

  char* ws = (char*)d_ws;
  u16* l6u = (u16*)(ws + OFF_L6U);
  int* idx1 = (int*)(ws + OFF_IDX1);
  float* dstate = (float*)(ws + OFF_FPSD);
  int* fstate = (int*)(ws + OFF_FPSI);
  u16* wb = (u16*)(ws + OFF_WB);
  float* outf = (float*)d_out;

  PrepArgs pa;
  const float* srcs[8] = {w1, w2, pc1_W, w3, w4, pc2_W, w5, w6};
  int Ns[8]  = {64, 256, 256, 256, 384, 384, 384, 512};
  int Ks[8]  = {4, 64, 256, 259, 256, 384, 387, 384};
  int Kps[8] = {32, 64, 256, 288, 256, 384, 416, 384};
  u16* WBp[8];
  int cum = 0;
  for (int i = 0; i < 8; ++i) {
    pa.wsrc[i] = srcs[i];
    pa.wdst[i] = WBp[i] = wb + cum;
    pa.wN[i] = Ns[i];
    pa.wK[i] = Ks[i];
    pa.wKp[i] = Kps[i];
    pa.wstart[i] = cum;
    cum += Ns[i] * Kps[i];
  }
  pa.wstart[8] = cum;
  int total = cum + 65536;

  // D1: weights + outf zero + FPS iters [0,64)
  prep_kernel<<<128 + (total + 255) / 256, 256, 0, stream>>>(
      pa, x, outf, init1, idx1, dstate, fstate, 64);

  // D2: fused A+B (500 MLP blocks, 128 rows each) + FPS iters [64,500)
  ABArgs A;
  A.w1 = WBp[0]; A.w2 = WBp[1]; A.pc1 = WBp[2];
  A.w3 = WBp[3]; A.w4 = WBp[4]; A.pc2 = WBp[5];
  A.b1 = b1; A.b2 = b2; A.pc1b = pc1_b; A.b3 = b3; A.b4 = b4; A.pc2b = pc2_b;
  fused_ab<<<128 + 500, 512, AB_LDS_BYTES, stream>>>(
      A, x, conf_W, conf_b, l6u, init1, idx1, dstate, fstate, 64, 436);

  // D3: fused C (gather + l7(LDS) + l8 + max), 128 rows/block
  CArgs Cg;
  Cg.w5 = WBp[6]; Cg.w6 = WBp[7]; Cg.b5 = b5; Cg.b6 = b6;
  fused_c<<<512, 512, C_LDS_BYTES, stream>>>(Cg, x, l6u, outf, idx1);
}